// Round 2
// baseline (1114.945 us; speedup 1.0000x reference)
//
#include <hip/hip_runtime.h>
#include <stdint.h>

#define NROWS 32768
#define KC 1024
#define DM 512
#define NKPROD 33554432u   // NROWS*KC

// ---------------- threefry2x32 (JAX-exact, key = (0, 42)) ----------------
__device__ __forceinline__ uint32_t rotl32(uint32_t x, int d) {
  return (x << d) | (x >> (32 - d));
}

__device__ __forceinline__ void threefry(uint32_t x0, uint32_t x1,
                                         uint32_t& o0, uint32_t& o1) {
  const uint32_t ks0 = 0u, ks1 = 42u, ks2 = 0x1BD11BF0u;  // 0^42^0x1BD11BDA
  x0 += ks0; x1 += ks1;
#define TFR(r) { x0 += x1; x1 = rotl32(x1, r); x1 ^= x0; }
  TFR(13) TFR(15) TFR(26) TFR(6)
  x0 += ks1; x1 += ks2 + 1u;
  TFR(17) TFR(29) TFR(16) TFR(24)
  x0 += ks2; x1 += ks0 + 2u;
  TFR(13) TFR(15) TFR(26) TFR(6)
  x0 += ks0; x1 += ks1 + 3u;
  TFR(17) TFR(29) TFR(16) TFR(24)
  x0 += ks1; x1 += ks2 + 4u;
  TFR(13) TFR(15) TFR(26) TFR(6)
  x0 += ks2; x1 += ks0 + 5u;
#undef TFR
  o0 = x0; o1 = x1;
}

// JAX uniform-in-[tiny,1) -> gumbel, bit-exact u construction
__device__ __forceinline__ float gumbel_bits(uint32_t b) {
  float f = __uint_as_float((b >> 9) | 0x3F800000u) - 1.0f;
  float u = fmaxf(1.17549435e-38f, f);
  return -logf(-logf(u));
}

// ---------------- mask dtype detection + normalization ----------------
__global__ __launch_bounds__(256) void k_detect(const uint8_t* __restrict__ m,
                                                uint32_t* __restrict__ flag) {
  uint32_t f = 0;
  for (int i = threadIdx.x; i < NROWS; i += 256)
    if ((i & 3) && m[i]) f = 1;   // nonzero high byte => 1-byte bool layout
  if (f) atomicOr(flag, 1u);
}

__global__ __launch_bounds__(256) void k_mask(const void* __restrict__ m,
                                              const uint32_t* __restrict__ flag,
                                              uint8_t* __restrict__ wm) {
  int n = blockIdx.x * 256 + threadIdx.x;
  bool p = (*flag) ? (((const uint8_t*)m)[n] != 0)
                   : (((const int*)m)[n] != 0);
  wm[n] = p ? 1u : 0u;
}

// ---------------- codebook row norms ----------------
__global__ __launch_bounds__(64) void k_cnorm(const float* __restrict__ B,
                                              float* __restrict__ cn) {
  int k = blockIdx.x, l = threadIdx.x;
  const float* bp = B + (size_t)k * DM + l * 8;
  float4 v0 = *(const float4*)bp, v1 = *(const float4*)(bp + 4);
  float s = v0.x*v0.x + v0.y*v0.y + v0.z*v0.z + v0.w*v0.w
          + v1.x*v1.x + v1.y*v1.y + v1.z*v1.z + v1.w*v1.w;
#pragma unroll
  for (int off = 32; off; off >>= 1) s += __shfl_xor(s, off, 64);
  if (l == 0) cn[k] = s;
}

// ---------------- logits GEMM: S[n,k] = -((||x||^2 + ||c||^2) - 2 x.c) ----------------
__global__ __launch_bounds__(256) void k_gemm(const float* __restrict__ A,
                                              const float* __restrict__ B,
                                              const float* __restrict__ cn,
                                              float* __restrict__ S) {
  __shared__ float As[8][128];
  __shared__ float Bs[8][128];
  __shared__ float rs[128];
  __shared__ float tmp[256];
  int tid = threadIdx.x;
  int bx = blockIdx.x & 7;
  int by = blockIdx.x >> 3;
  int r0 = by * 128, c0 = bx * 128;
  int tx = tid & 15, ty = tid >> 4;
  int lrow = tid >> 1, loff = (tid & 1) * 4;

  // per-row ||x||^2 (two threads per row)
  {
    const float* ap = A + (size_t)(r0 + lrow) * DM + (tid & 1) * 256;
    float sacc = 0.f;
    for (int i = 0; i < 256; i += 4) {
      float4 v = *(const float4*)(ap + i);
      sacc = fmaf(v.x, v.x, sacc); sacc = fmaf(v.y, v.y, sacc);
      sacc = fmaf(v.z, v.z, sacc); sacc = fmaf(v.w, v.w, sacc);
    }
    tmp[tid] = sacc;
    __syncthreads();
    if ((tid & 1) == 0) rs[lrow] = tmp[tid] + tmp[tid + 1];
    __syncthreads();
  }

  float acc[8][8];
#pragma unroll
  for (int i = 0; i < 8; ++i)
#pragma unroll
    for (int j = 0; j < 8; ++j) acc[i][j] = 0.f;

  const float* aip = A + (size_t)(r0 + lrow) * DM + loff;
  const float* bip = B + (size_t)(c0 + lrow) * DM + loff;
  for (int k0 = 0; k0 < DM; k0 += 8) {
    float4 av = *(const float4*)(aip + k0);
    float4 bv = *(const float4*)(bip + k0);
    As[loff + 0][lrow] = av.x; As[loff + 1][lrow] = av.y;
    As[loff + 2][lrow] = av.z; As[loff + 3][lrow] = av.w;
    Bs[loff + 0][lrow] = bv.x; Bs[loff + 1][lrow] = bv.y;
    Bs[loff + 2][lrow] = bv.z; Bs[loff + 3][lrow] = bv.w;
    __syncthreads();
#pragma unroll
    for (int kk = 0; kk < 8; ++kk) {
      float ar[8], br[8];
      *(float4*)&ar[0] = *(const float4*)&As[kk][ty * 8];
      *(float4*)&ar[4] = *(const float4*)&As[kk][ty * 8 + 4];
      *(float4*)&br[0] = *(const float4*)&Bs[kk][tx * 8];
      *(float4*)&br[4] = *(const float4*)&Bs[kk][tx * 8 + 4];
#pragma unroll
      for (int i = 0; i < 8; ++i)
#pragma unroll
        for (int j = 0; j < 8; ++j)
          acc[i][j] = fmaf(ar[i], br[j], acc[i][j]);
    }
    __syncthreads();
  }

  float cnp[8];
#pragma unroll
  for (int j = 0; j < 8; ++j) cnp[j] = cn[c0 + tx * 8 + j];
#pragma unroll
  for (int i = 0; i < 8; ++i) {
    int r = ty * 8 + i;
    float rq = rs[r];
    float o[8];
#pragma unroll
    for (int j = 0; j < 8; ++j)
      o[j] = -((rq + cnp[j]) - 2.0f * acc[i][j]);
    float* sp = S + (size_t)(r0 + r) * KC + c0 + tx * 8;
    *(float4*)sp       = make_float4(o[0], o[1], o[2], o[3]);
    *(float4*)(sp + 4) = make_float4(o[4], o[5], o[6], o[7]);
  }
}

// ---------------- sampling + outputs (one wave per row) ----------------
// Partitionable-threefry bits: element t of the (10,N,K) gumbel tensor gets
// bits = o0 ^ o1 of threefry(key, (hi32(t)=0, lo32(t)=t)).
__global__ __launch_bounds__(64) void k_sample(
    const float* __restrict__ S, const float* __restrict__ X,
    const float* __restrict__ CW, const uint8_t* __restrict__ wm,
    float* __restrict__ qout, float* __restrict__ sout,
    float* __restrict__ cnt, double* __restrict__ esum) {
  int n = blockIdx.x;
  int l = threadIdx.x;
  bool pad = wm[n] != 0;
  const float* srow = S + (size_t)n * KC;
  int base = l * 16;
  float lg[16];
#pragma unroll
  for (int j = 0; j < 16; j += 4)
    *(float4*)&lg[j] = *(const float4*)(srow + base + j);
  if (l == 0) lg[0] = -__builtin_inff();  // code 0 disallowed for non-pad rows

  uint32_t win[10];
#pragma unroll
  for (int s = 0; s < 10; ++s) win[s] = 0;

  if (!pad) {
#pragma unroll 1
    for (int s = 0; s < 10; ++s) {
      float bv = -__builtin_inff();
      uint32_t bi = 0xFFFFFFFFu;
      uint32_t tb = (uint32_t)s * NKPROD + (uint32_t)n * (uint32_t)KC + (uint32_t)base;
#pragma unroll 4
      for (int j = 0; j < 16; ++j) {
        uint32_t o0, o1;
        threefry(0u, tb + (uint32_t)j, o0, o1);
        float v = gumbel_bits(o0 ^ o1) + lg[j];
        if (v > bv) { bv = v; bi = (uint32_t)(base + j); }
      }
#pragma unroll
      for (int off = 32; off; off >>= 1) {
        float ov = __shfl_xor(bv, off, 64);
        uint32_t oi = __shfl_xor(bi, off, 64);
        if (ov > bv || (ov == bv && oi < bi)) { bv = ov; bi = oi; }
      }
      win[s] = bi;
    }
  }

  // counts: overwrite this row's logits with sample counts
  float* so = sout + (size_t)n * KC + base;
#pragma unroll
  for (int j4 = 0; j4 < 16; j4 += 4) {
    float c[4];
#pragma unroll
    for (int i = 0; i < 4; ++i) {
      uint32_t k = (uint32_t)(base + j4 + i);
      float cc = 0.f;
#pragma unroll
      for (int s = 0; s < 10; ++s) cc += (win[s] == k) ? 1.f : 0.f;
      c[i] = cc;
    }
    *(float4*)(so + j4) = make_float4(c[0], c[1], c[2], c[3]);
  }

  // quantized (sum of the 10 drawn codebook rows / 10) + straight-through + loss
  float q[8] = {0, 0, 0, 0, 0, 0, 0, 0};
#pragma unroll
  for (int s = 0; s < 10; ++s) {
    const float* cr = CW + (size_t)win[s] * DM + l * 8;
    float4 c0 = *(const float4*)cr;
    float4 c1 = *(const float4*)(cr + 4);
    q[0] += c0.x; q[1] += c0.y; q[2] += c0.z; q[3] += c0.w;
    q[4] += c1.x; q[5] += c1.y; q[6] += c1.z; q[7] += c1.w;
  }
  const float* xr = X + (size_t)n * DM + l * 8;
  float4 x0 = *(const float4*)xr, x1 = *(const float4*)(xr + 4);
  float xs[8] = {x0.x, x0.y, x0.z, x0.w, x1.x, x1.y, x1.z, x1.w};
  float st[8];
  double ls = 0.0;
#pragma unroll
  for (int j = 0; j < 8; ++j) {
    float qq = q[j] / 10.0f;
    float d = qq - xs[j];
    ls += (double)(d * d);
    st[j] = xs[j] + d;
  }
  float* qo = qout + (size_t)n * DM + l * 8;
  *(float4*)qo       = make_float4(st[0], st[1], st[2], st[3]);
  *(float4*)(qo + 4) = make_float4(st[4], st[5], st[6], st[7]);

#pragma unroll
  for (int off = 32; off; off >>= 1) ls += __shfl_xor(ls, off, 64);
  if (l == 0) {
    atomicAdd(esum, ls);
    if (!pad) {
#pragma unroll
      for (int s = 0; s < 10; ++s) atomicAdd(&cnt[win[s]], 1.0f);
    }
  }
}

// ---------------- scalars: loss + perplexity ----------------
__global__ __launch_bounds__(256) void k_final(const uint8_t* __restrict__ wm,
                                               const float* __restrict__ cnt,
                                               const double* __restrict__ esum,
                                               float* __restrict__ scal) {
  __shared__ int sni[256];
  __shared__ double snd[256];
  int t = threadIdx.x;
  int np = 0;
  for (int i = t; i < NROWS; i += 256) np += wm[i];
  sni[t] = np;
  __syncthreads();
  for (int off = 128; off; off >>= 1) {
    if (t < off) sni[t] += sni[t + off];
    __syncthreads();
  }
  int npad = sni[0];
  double ss = 0.0;
  for (int k = t; k < KC; k += 256) {
    float c = (k == 0) ? (float)(npad * 10) : cnt[k];
    float p = c / 327680.0f;   // / (N * NUM_SAMPLES)
    ss += (double)(p * logf(p + 1e-10f));
  }
  snd[t] = ss;
  __syncthreads();
  for (int off = 128; off; off >>= 1) {
    if (t < off) snd[t] += snd[t + off];
    __syncthreads();
  }
  if (t == 0) {
    float num_nonpad = (float)((NROWS - npad) * DM);
    float el = (float)(*esum) / num_nonpad;
    scal[0] = 0.25f * el;               // loss
    scal[1] = expf(-(float)snd[0]);     // perplexity
  }
}

extern "C" void kernel_launch(void* const* d_in, const int* in_sizes, int n_in,
                              void* d_out, int out_size, void* d_ws, size_t ws_size,
                              hipStream_t stream) {
  const float* X  = (const float*)d_in[0];
  const void*  M  = d_in[1];
  const float* CW = (const float*)d_in[2];
  float* out  = (float*)d_out;
  float* qout = out;                    // [0, 16777216): quantized_st
  float* sout = out + 16777216;         // [.., 50331648): logits scratch -> samples
  float* scal = out + 50331648;         // loss, perplexity
  uint8_t* ws = (uint8_t*)d_ws;
  double*   esum = (double*)ws;         // 8 B
  uint32_t* flag = (uint32_t*)(ws + 8); // 4 B
  float*    cnt  = (float*)(ws + 16);   // 4 KB (per-code totals)
  uint8_t*  wm   = ws + 8192;           // 32 KB (normalized byte mask)
  (void)in_sizes; (void)n_in; (void)out_size; (void)ws_size;

  hipMemsetAsync(d_ws, 0, 40960, stream);
  k_detect<<<1, 256, 0, stream>>>((const uint8_t*)M, flag);
  k_mask<<<128, 256, 0, stream>>>(M, flag, wm);
  k_cnorm<<<KC, 64, 0, stream>>>(CW, qout);              // cnorm scratch in quantized region
  k_gemm<<<2048, 256, 0, stream>>>(X, CW, qout, sout);   // logits into samples region
  k_sample<<<NROWS, 64, 0, stream>>>(sout, X, CW, wm, qout, sout, cnt, esum);
  k_final<<<1, 256, 0, stream>>>(wm, cnt, esum, scal);
}

// Round 3
// 880.375 us; speedup vs baseline: 1.2664x; 1.2664x over previous
//
#include <hip/hip_runtime.h>
#include <stdint.h>

#define NROWS 32768
#define KC 1024
#define DM 512
#define NKPROD 33554432u   // NROWS*KC

typedef _Float16 v8h __attribute__((ext_vector_type(8)));
typedef float v4f __attribute__((ext_vector_type(4)));

// ---------------- threefry2x32 (JAX-exact, key = (0, 42)) ----------------
__device__ __forceinline__ uint32_t rotl32(uint32_t x, int d) {
  return (x << d) | (x >> (32 - d));
}

__device__ __forceinline__ void threefry(uint32_t x0, uint32_t x1,
                                         uint32_t& o0, uint32_t& o1) {
  const uint32_t ks0 = 0u, ks1 = 42u, ks2 = 0x1BD11BF0u;  // 0^42^0x1BD11BDA
  x0 += ks0; x1 += ks1;
#define TFR(r) { x0 += x1; x1 = rotl32(x1, r); x1 ^= x0; }
  TFR(13) TFR(15) TFR(26) TFR(6)
  x0 += ks1; x1 += ks2 + 1u;
  TFR(17) TFR(29) TFR(16) TFR(24)
  x0 += ks2; x1 += ks0 + 2u;
  TFR(13) TFR(15) TFR(26) TFR(6)
  x0 += ks0; x1 += ks1 + 3u;
  TFR(17) TFR(29) TFR(16) TFR(24)
  x0 += ks1; x1 += ks2 + 4u;
  TFR(13) TFR(15) TFR(26) TFR(6)
  x0 += ks2; x1 += ks0 + 5u;
#undef TFR
  o0 = x0; o1 = x1;
}

// JAX uniform-in-[tiny,1) -> gumbel, bit-exact u construction
__device__ __forceinline__ float gumbel_bits(uint32_t b) {
  float f = __uint_as_float((b >> 9) | 0x3F800000u) - 1.0f;
  float u = fmaxf(1.17549435e-38f, f);
  return -logf(-logf(u));
}

// ---------------- mask dtype detection + normalization ----------------
__global__ __launch_bounds__(256) void k_detect(const uint8_t* __restrict__ m,
                                                uint32_t* __restrict__ flag) {
  uint32_t f = 0;
  for (int i = threadIdx.x; i < NROWS; i += 256)
    if ((i & 3) && m[i]) f = 1;   // nonzero high byte => 1-byte bool layout
  if (f) atomicOr(flag, 1u);
}

__global__ __launch_bounds__(256) void k_mask(const void* __restrict__ m,
                                              const uint32_t* __restrict__ flag,
                                              uint8_t* __restrict__ wm) {
  int n = blockIdx.x * 256 + threadIdx.x;
  bool p = (*flag) ? (((const uint8_t*)m)[n] != 0)
                   : (((const int*)m)[n] != 0);
  wm[n] = p ? 1u : 0u;
}

// ---------------- codebook row norms ----------------
__global__ __launch_bounds__(64) void k_cnorm(const float* __restrict__ B,
                                              float* __restrict__ cn) {
  int k = blockIdx.x, l = threadIdx.x;
  const float* bp = B + (size_t)k * DM + l * 8;
  float4 v0 = *(const float4*)bp, v1 = *(const float4*)(bp + 4);
  float s = v0.x*v0.x + v0.y*v0.y + v0.z*v0.z + v0.w*v0.w
          + v1.x*v1.x + v1.y*v1.y + v1.z*v1.z + v1.w*v1.w;
#pragma unroll
  for (int off = 32; off; off >>= 1) s += __shfl_xor(s, off, 64);
  if (l == 0) cn[k] = s;
}

// ---------------- logits GEMM (MFMA, f16 two-term split) ----------------
// S[n,k] = -((||x||^2 + ||c||^2) - 2 x.c), dot via hi*hi + hi*lo + lo*hi.
#define LDK 40   // padded BK stride in f16 (80 B, 16B-aligned, conflict-light)
__global__ __launch_bounds__(256) void k_gemm2(const float* __restrict__ A,
                                               const float* __restrict__ B,
                                               const float* __restrict__ cn,
                                               float* __restrict__ S) {
  __shared__ _Float16 Ah[128 * LDK], Al[128 * LDK];
  __shared__ _Float16 Bh[128 * LDK], Bl[128 * LDK];
  __shared__ float rs[128];
  __shared__ float tmp[256];

  int tid = threadIdx.x;
  int bx = blockIdx.x & 7;           // N panel (consecutive bids share A-panel)
  int by = blockIdx.x >> 3;          // M panel
  int r0 = by * 128, c0 = bx * 128;

  int wid = tid >> 6;
  int wr = wid >> 1, wc = wid & 1;   // wave sub-tile (64x64)
  int l = tid & 63;
  int lr = l & 15;
  int k8 = (l >> 4) * 8;

  int srow = tid >> 1;               // staging row 0..127
  int ssub = (tid & 1) * 16;         // staging k sub-offset

  const float* ag = A + (size_t)(r0 + srow) * DM + ssub;
  const float* bg = B + (size_t)(c0 + srow) * DM + ssub;

  v4f acc[4][4];
#pragma unroll
  for (int m = 0; m < 4; ++m)
#pragma unroll
    for (int n = 0; n < 4; ++n) acc[m][n] = (v4f)0.0f;

  float sqa = 0.f;

  for (int k0 = 0; k0 < DM; k0 += 32) {
    // load + split
    float xa[16], xb[16];
#pragma unroll
    for (int i = 0; i < 16; i += 4) {
      *(float4*)&xa[i] = *(const float4*)(ag + k0 + i);
      *(float4*)&xb[i] = *(const float4*)(bg + k0 + i);
    }
    _Float16 ha[16], la[16], hb[16], lb[16];
#pragma unroll
    for (int i = 0; i < 16; ++i) {
      float x = xa[i];
      _Float16 h = (_Float16)x;
      ha[i] = h; la[i] = (_Float16)(x - (float)h);
      sqa = fmaf(x, x, sqa);
      float y = xb[i];
      _Float16 g = (_Float16)y;
      hb[i] = g; lb[i] = (_Float16)(y - (float)g);
    }
    __syncthreads();   // previous iter's frag reads done
    int wb = srow * LDK + ssub;
    *(v8h*)&Ah[wb]     = *(v8h*)&ha[0];
    *(v8h*)&Ah[wb + 8] = *(v8h*)&ha[8];
    *(v8h*)&Al[wb]     = *(v8h*)&la[0];
    *(v8h*)&Al[wb + 8] = *(v8h*)&la[8];
    *(v8h*)&Bh[wb]     = *(v8h*)&hb[0];
    *(v8h*)&Bh[wb + 8] = *(v8h*)&hb[8];
    *(v8h*)&Bl[wb]     = *(v8h*)&lb[0];
    *(v8h*)&Bl[wb + 8] = *(v8h*)&lb[8];
    __syncthreads();

    v8h fah[4], fal[4];
#pragma unroll
    for (int m = 0; m < 4; ++m) {
      int row = wr * 64 + m * 16 + lr;
      fah[m] = *(const v8h*)&Ah[row * LDK + k8];
      fal[m] = *(const v8h*)&Al[row * LDK + k8];
    }
#pragma unroll
    for (int n = 0; n < 4; ++n) {
      int col = wc * 64 + n * 16 + lr;
      v8h fbh = *(const v8h*)&Bh[col * LDK + k8];
      v8h fbl = *(const v8h*)&Bl[col * LDK + k8];
#pragma unroll
      for (int m = 0; m < 4; ++m) {
        acc[m][n] = __builtin_amdgcn_mfma_f32_16x16x32_f16(fah[m], fbh, acc[m][n], 0, 0, 0);
        acc[m][n] = __builtin_amdgcn_mfma_f32_16x16x32_f16(fah[m], fbl, acc[m][n], 0, 0, 0);
        acc[m][n] = __builtin_amdgcn_mfma_f32_16x16x32_f16(fal[m], fbh, acc[m][n], 0, 0, 0);
      }
    }
  }

  // row norms (fused: each thread summed its staged A elements)
  tmp[tid] = sqa;
  __syncthreads();
  if ((tid & 1) == 0) rs[srow] = tmp[tid] + tmp[tid + 1];
  __syncthreads();

  float cnp[4];
#pragma unroll
  for (int n = 0; n < 4; ++n) cnp[n] = cn[c0 + wc * 64 + n * 16 + lr];

#pragma unroll
  for (int m = 0; m < 4; ++m) {
    int rl = wr * 64 + m * 16 + (l >> 4) * 4;
#pragma unroll
    for (int r = 0; r < 4; ++r) {
      float rq = rs[rl + r];
      float* sp = S + (size_t)(r0 + rl + r) * KC + c0;
#pragma unroll
      for (int n = 0; n < 4; ++n) {
        int cl = wc * 64 + n * 16 + lr;
        sp[cl] = -((rq + cnp[n]) - 2.0f * acc[m][n][r]);
      }
    }
  }
}

// ---------------- sampling + outputs (4 rows/block, one wave each) ----------------
// Partitionable-threefry bits: element t of the (10,N,K) gumbel tensor gets
// bits = o0 ^ o1 of threefry(key, (hi32(t)=0, lo32(t)=t)).
__global__ __launch_bounds__(256) void k_sample(
    const float* __restrict__ S, const float* __restrict__ X,
    const float* __restrict__ CW, const uint8_t* __restrict__ wm,
    float* __restrict__ qout, float* __restrict__ sout,
    float* __restrict__ cnt, double* __restrict__ esum) {
  __shared__ double lsum[4];
  int tid = threadIdx.x;
  int n = blockIdx.x * 4 + (tid >> 6);
  int l = tid & 63;
  bool pad = wm[n] != 0;
  const float* srow = S + (size_t)n * KC;
  int base = l * 16;
  float lg[16];
#pragma unroll
  for (int j = 0; j < 16; j += 4)
    *(float4*)&lg[j] = *(const float4*)(srow + base + j);
  if (l == 0) lg[0] = -__builtin_inff();  // code 0 disallowed for non-pad rows

  uint32_t win[10];
#pragma unroll
  for (int s = 0; s < 10; ++s) win[s] = 0;

  if (!pad) {
#pragma unroll 1
    for (int s = 0; s < 10; ++s) {
      float bv = -__builtin_inff();
      uint32_t bi = 0xFFFFFFFFu;
      uint32_t tb = (uint32_t)s * NKPROD + (uint32_t)n * (uint32_t)KC + (uint32_t)base;
#pragma unroll 4
      for (int j = 0; j < 16; ++j) {
        uint32_t o0, o1;
        threefry(0u, tb + (uint32_t)j, o0, o1);
        float v = gumbel_bits(o0 ^ o1) + lg[j];
        if (v > bv) { bv = v; bi = (uint32_t)(base + j); }
      }
#pragma unroll
      for (int off = 32; off; off >>= 1) {
        float ov = __shfl_xor(bv, off, 64);
        uint32_t oi = __shfl_xor(bi, off, 64);
        if (ov > bv || (ov == bv && oi < bi)) { bv = ov; bi = oi; }
      }
      win[s] = bi;
    }
  }

  // counts: overwrite this row's logits with sample counts
  float* so = sout + (size_t)n * KC + base;
#pragma unroll
  for (int j4 = 0; j4 < 16; j4 += 4) {
    float c[4];
#pragma unroll
    for (int i = 0; i < 4; ++i) {
      uint32_t k = (uint32_t)(base + j4 + i);
      float cc = 0.f;
#pragma unroll
      for (int s = 0; s < 10; ++s) cc += (win[s] == k) ? 1.f : 0.f;
      c[i] = cc;
    }
    *(float4*)(so + j4) = make_float4(c[0], c[1], c[2], c[3]);
  }

  // quantized (sum of the 10 drawn codebook rows / 10) + straight-through + loss
  float q[8] = {0, 0, 0, 0, 0, 0, 0, 0};
#pragma unroll
  for (int s = 0; s < 10; ++s) {
    const float* cr = CW + (size_t)win[s] * DM + l * 8;
    float4 c0 = *(const float4*)cr;
    float4 c1 = *(const float4*)(cr + 4);
    q[0] += c0.x; q[1] += c0.y; q[2] += c0.z; q[3] += c0.w;
    q[4] += c1.x; q[5] += c1.y; q[6] += c1.z; q[7] += c1.w;
  }
  const float* xr = X + (size_t)n * DM + l * 8;
  float4 x0 = *(const float4*)xr, x1 = *(const float4*)(xr + 4);
  float xs[8] = {x0.x, x0.y, x0.z, x0.w, x1.x, x1.y, x1.z, x1.w};
  float st[8];
  double ls = 0.0;
#pragma unroll
  for (int j = 0; j < 8; ++j) {
    float qq = q[j] / 10.0f;
    float d = qq - xs[j];
    ls += (double)(d * d);
    st[j] = xs[j] + d;
  }
  float* qo = qout + (size_t)n * DM + l * 8;
  *(float4*)qo       = make_float4(st[0], st[1], st[2], st[3]);
  *(float4*)(qo + 4) = make_float4(st[4], st[5], st[6], st[7]);

#pragma unroll
  for (int off = 32; off; off >>= 1) ls += __shfl_xor(ls, off, 64);
  if (l == 0) {
    lsum[tid >> 6] = ls;
    if (!pad) {
#pragma unroll
      for (int s = 0; s < 10; ++s) atomicAdd(&cnt[win[s]], 1.0f);
    }
  }
  __syncthreads();
  if (tid == 0) atomicAdd(esum, lsum[0] + lsum[1] + lsum[2] + lsum[3]);
}

// ---------------- scalars: loss + perplexity ----------------
__global__ __launch_bounds__(256) void k_final(const uint8_t* __restrict__ wm,
                                               const float* __restrict__ cnt,
                                               const double* __restrict__ esum,
                                               float* __restrict__ scal) {
  __shared__ int sni[256];
  __shared__ double snd[256];
  int t = threadIdx.x;
  int np = 0;
  for (int i = t; i < NROWS; i += 256) np += wm[i];
  sni[t] = np;
  __syncthreads();
  for (int off = 128; off; off >>= 1) {
    if (t < off) sni[t] += sni[t + off];
    __syncthreads();
  }
  int npad = sni[0];
  double ss = 0.0;
  for (int k = t; k < KC; k += 256) {
    float c = (k == 0) ? (float)(npad * 10) : cnt[k];
    float p = c / 327680.0f;   // / (N * NUM_SAMPLES)
    ss += (double)(p * logf(p + 1e-10f));
  }
  snd[t] = ss;
  __syncthreads();
  for (int off = 128; off; off >>= 1) {
    if (t < off) snd[t] += snd[t + off];
    __syncthreads();
  }
  if (t == 0) {
    float num_nonpad = (float)((NROWS - npad) * DM);
    float el = (float)(*esum) / num_nonpad;
    scal[0] = 0.25f * el;               // loss
    scal[1] = expf(-(float)snd[0]);     // perplexity
  }
}

extern "C" void kernel_launch(void* const* d_in, const int* in_sizes, int n_in,
                              void* d_out, int out_size, void* d_ws, size_t ws_size,
                              hipStream_t stream) {
  const float* X  = (const float*)d_in[0];
  const void*  M  = d_in[1];
  const float* CW = (const float*)d_in[2];
  float* out  = (float*)d_out;
  float* qout = out;                    // [0, 16777216): quantized_st
  float* sout = out + 16777216;         // [.., 50331648): logits scratch -> samples
  float* scal = out + 50331648;         // loss, perplexity
  uint8_t* ws = (uint8_t*)d_ws;
  double*   esum = (double*)ws;         // 8 B
  uint32_t* flag = (uint32_t*)(ws + 8); // 4 B
  float*    cnt  = (float*)(ws + 16);   // 4 KB (per-code totals)
  uint8_t*  wm   = ws + 8192;           // 32 KB (normalized byte mask)
  float*    cng  = (float*)(ws + 40960);// 4 KB (codebook row norms)
  (void)in_sizes; (void)n_in; (void)out_size; (void)ws_size;

  hipMemsetAsync(d_ws, 0, 45056, stream);
  k_detect<<<1, 256, 0, stream>>>((const uint8_t*)M, flag);
  k_mask<<<128, 256, 0, stream>>>(M, flag, wm);
  k_cnorm<<<KC, 64, 0, stream>>>(CW, cng);
  k_gemm2<<<2048, 256, 0, stream>>>(X, CW, cng, sout);   // logits into samples region
  k_sample<<<8192, 256, 0, stream>>>(sout, X, CW, wm, qout, sout, cnt, esum);
  k_final<<<1, 256, 0, stream>>>(wm, cnt, esum, scal);
}

// Round 4
// 670.624 us; speedup vs baseline: 1.6625x; 1.3128x over previous
//
#include <hip/hip_runtime.h>
#include <stdint.h>

#define NROWS 32768
#define KC 1024
#define DM 512
#define NKPROD 33554432u   // NROWS*KC

typedef _Float16 v8h __attribute__((ext_vector_type(8)));
typedef float v4f __attribute__((ext_vector_type(4)));

// ---------------- threefry2x32 (JAX-exact, key = (0, 42)) ----------------
__device__ __forceinline__ uint32_t rotl32(uint32_t x, int d) {
  return (x << d) | (x >> (32 - d));
}

__device__ __forceinline__ void threefry(uint32_t x0, uint32_t x1,
                                         uint32_t& o0, uint32_t& o1) {
  const uint32_t ks0 = 0u, ks1 = 42u, ks2 = 0x1BD11BF0u;  // 0^42^0x1BD11BDA
  x0 += ks0; x1 += ks1;
#define TFR(r) { x0 += x1; x1 = rotl32(x1, r); x1 ^= x0; }
  TFR(13) TFR(15) TFR(26) TFR(6)
  x0 += ks1; x1 += ks2 + 1u;
  TFR(17) TFR(29) TFR(16) TFR(24)
  x0 += ks2; x1 += ks0 + 2u;
  TFR(13) TFR(15) TFR(26) TFR(6)
  x0 += ks0; x1 += ks1 + 3u;
  TFR(17) TFR(29) TFR(16) TFR(24)
  x0 += ks1; x1 += ks2 + 4u;
  TFR(13) TFR(15) TFR(26) TFR(6)
  x0 += ks2; x1 += ks0 + 5u;
#undef TFR
  o0 = x0; o1 = x1;
}

// ---------------- mask dtype detection + normalization ----------------
__global__ __launch_bounds__(256) void k_detect(const uint8_t* __restrict__ m,
                                                uint32_t* __restrict__ flag) {
  uint32_t f = 0;
  for (int i = threadIdx.x; i < NROWS; i += 256)
    if ((i & 3) && m[i]) f = 1;   // nonzero high byte => 1-byte bool layout
  if (f) atomicOr(flag, 1u);
}

__global__ __launch_bounds__(256) void k_mask(const void* __restrict__ m,
                                              const uint32_t* __restrict__ flag,
                                              uint8_t* __restrict__ wm) {
  int n = blockIdx.x * 256 + threadIdx.x;
  bool p = (*flag) ? (((const uint8_t*)m)[n] != 0)
                   : (((const int*)m)[n] != 0);
  wm[n] = p ? 1u : 0u;
}

// ---------------- codebook row norms ----------------
__global__ __launch_bounds__(64) void k_cnorm(const float* __restrict__ B,
                                              float* __restrict__ cn) {
  int k = blockIdx.x, l = threadIdx.x;
  const float* bp = B + (size_t)k * DM + l * 8;
  float4 v0 = *(const float4*)bp, v1 = *(const float4*)(bp + 4);
  float s = v0.x*v0.x + v0.y*v0.y + v0.z*v0.z + v0.w*v0.w
          + v1.x*v1.x + v1.y*v1.y + v1.z*v1.z + v1.w*v1.w;
#pragma unroll
  for (int off = 32; off; off >>= 1) s += __shfl_xor(s, off, 64);
  if (l == 0) cn[k] = s;
}

// ---------------- logits GEMM (MFMA, f16 two-term split) ----------------
// S[n,k] = -((||x||^2 + ||c||^2) - 2 x.c), dot via hi*hi + hi*lo + lo*hi.
#define LDK 40   // padded BK stride in f16 (80 B, 16B-aligned, conflict-light)
__global__ __launch_bounds__(256) void k_gemm2(const float* __restrict__ A,
                                               const float* __restrict__ B,
                                               const float* __restrict__ cn,
                                               float* __restrict__ S) {
  __shared__ _Float16 Ah[128 * LDK], Al[128 * LDK];
  __shared__ _Float16 Bh[128 * LDK], Bl[128 * LDK];
  __shared__ float rs[128];
  __shared__ float tmp[256];

  int tid = threadIdx.x;
  int bx = blockIdx.x & 7;           // N panel (consecutive bids share A-panel)
  int by = blockIdx.x >> 3;          // M panel
  int r0 = by * 128, c0 = bx * 128;

  int wid = tid >> 6;
  int wr = wid >> 1, wc = wid & 1;   // wave sub-tile (64x64)
  int l = tid & 63;
  int lr = l & 15;
  int k8 = (l >> 4) * 8;

  int srow = tid >> 1;               // staging row 0..127
  int ssub = (tid & 1) * 16;         // staging k sub-offset

  const float* ag = A + (size_t)(r0 + srow) * DM + ssub;
  const float* bg = B + (size_t)(c0 + srow) * DM + ssub;

  v4f acc[4][4];
#pragma unroll
  for (int m = 0; m < 4; ++m)
#pragma unroll
    for (int n = 0; n < 4; ++n) acc[m][n] = (v4f)0.0f;

  float sqa = 0.f;

  for (int k0 = 0; k0 < DM; k0 += 32) {
    // load + split
    float xa[16], xb[16];
#pragma unroll
    for (int i = 0; i < 16; i += 4) {
      *(float4*)&xa[i] = *(const float4*)(ag + k0 + i);
      *(float4*)&xb[i] = *(const float4*)(bg + k0 + i);
    }
    _Float16 ha[16], la[16], hb[16], lb[16];
#pragma unroll
    for (int i = 0; i < 16; ++i) {
      float x = xa[i];
      _Float16 h = (_Float16)x;
      ha[i] = h; la[i] = (_Float16)(x - (float)h);
      sqa = fmaf(x, x, sqa);
      float y = xb[i];
      _Float16 g = (_Float16)y;
      hb[i] = g; lb[i] = (_Float16)(y - (float)g);
    }
    __syncthreads();   // previous iter's frag reads done
    int wb = srow * LDK + ssub;
    *(v8h*)&Ah[wb]     = *(v8h*)&ha[0];
    *(v8h*)&Ah[wb + 8] = *(v8h*)&ha[8];
    *(v8h*)&Al[wb]     = *(v8h*)&la[0];
    *(v8h*)&Al[wb + 8] = *(v8h*)&la[8];
    *(v8h*)&Bh[wb]     = *(v8h*)&hb[0];
    *(v8h*)&Bh[wb + 8] = *(v8h*)&hb[8];
    *(v8h*)&Bl[wb]     = *(v8h*)&lb[0];
    *(v8h*)&Bl[wb + 8] = *(v8h*)&lb[8];
    __syncthreads();

    v8h fah[4], fal[4];
#pragma unroll
    for (int m = 0; m < 4; ++m) {
      int row = wr * 64 + m * 16 + lr;
      fah[m] = *(const v8h*)&Ah[row * LDK + k8];
      fal[m] = *(const v8h*)&Al[row * LDK + k8];
    }
#pragma unroll
    for (int n = 0; n < 4; ++n) {
      int col = wc * 64 + n * 16 + lr;
      v8h fbh = *(const v8h*)&Bh[col * LDK + k8];
      v8h fbl = *(const v8h*)&Bl[col * LDK + k8];
#pragma unroll
      for (int m = 0; m < 4; ++m) {
        acc[m][n] = __builtin_amdgcn_mfma_f32_16x16x32_f16(fah[m], fbh, acc[m][n], 0, 0, 0);
        acc[m][n] = __builtin_amdgcn_mfma_f32_16x16x32_f16(fah[m], fbl, acc[m][n], 0, 0, 0);
        acc[m][n] = __builtin_amdgcn_mfma_f32_16x16x32_f16(fal[m], fbh, acc[m][n], 0, 0, 0);
      }
    }
  }

  // row norms (fused: each thread summed its staged A elements)
  tmp[tid] = sqa;
  __syncthreads();
  if ((tid & 1) == 0) rs[srow] = tmp[tid] + tmp[tid + 1];
  __syncthreads();

  float cnp[4];
#pragma unroll
  for (int n = 0; n < 4; ++n) cnp[n] = cn[c0 + wc * 64 + n * 16 + lr];

#pragma unroll
  for (int m = 0; m < 4; ++m) {
    int rl = wr * 64 + m * 16 + (l >> 4) * 4;
#pragma unroll
    for (int r = 0; r < 4; ++r) {
      float rq = rs[rl + r];
      float* sp = S + (size_t)(r0 + rl + r) * KC + c0;
#pragma unroll
      for (int n = 0; n < 4; ++n) {
        int cl = wc * 64 + n * 16 + lr;
        sp[cl] = -((rq + cnp[n]) - 2.0f * acc[m][n][r]);
      }
    }
  }
}

// ---------------- sampling + outputs (4 rows/block, one wave each) ----------------
// Partitionable-threefry bits: element t of the (10,N,K) gumbel tensor gets
// bits = o0 ^ o1 of threefry(key, (0, t)).
// argmax_k(g_k + l_k) == argmax_k fl(log2(u_k) * m_k), m_k = ln2*exp(lmax-l_k)
// (exact-math monotone: v = -exp(-(g+l'))). All state in registers: j-loop
// fully unrolled, counts kept as 16 per-lane regs, cnt atomics in-loop.
__global__ __launch_bounds__(256) void k_sample(
    const float* __restrict__ S, const float* __restrict__ X,
    const float* __restrict__ CW, const uint8_t* __restrict__ wm,
    float* __restrict__ qout, float* __restrict__ sout,
    float* __restrict__ cnt, double* __restrict__ esum) {
  __shared__ double lsum[4];
  int tid = threadIdx.x;
  int n = blockIdx.x * 4 + (tid >> 6);
  int l = tid & 63;
  int base = l * 16;
  bool pad = wm[n] != 0;

  float c[16];
#pragma unroll
  for (int i = 0; i < 16; ++i) c[i] = 0.f;
  float q[8];
#pragma unroll
  for (int i = 0; i < 8; ++i) q[i] = 0.f;

  if (!pad) {
    const float* srow = S + (size_t)n * KC + base;
    float lg[16];
#pragma unroll
    for (int j = 0; j < 16; j += 4)
      *(float4*)&lg[j] = *(const float4*)(srow + j);
    if (l == 0) lg[0] = -__builtin_inff();  // code 0 disallowed

    float lmax = lg[0];
#pragma unroll
    for (int i = 1; i < 16; ++i) lmax = fmaxf(lmax, lg[i]);
#pragma unroll
    for (int off = 32; off; off >>= 1)
      lmax = fmaxf(lmax, __shfl_xor(lmax, off, 64));

    float m[16];
#pragma unroll
    for (int i = 0; i < 16; ++i)
      m[i] = 0.69314718056f * __expf(lmax - lg[i]);  // lane0 i=0 -> inf (never wins)

#pragma unroll 1
    for (int s = 0; s < 10; ++s) {
      uint32_t tb = (uint32_t)s * NKPROD + (uint32_t)n * (uint32_t)KC + (uint32_t)base;
      float bv = -__builtin_inff();
      uint32_t bi = 0xFFFFFFFFu;
#pragma unroll
      for (int j = 0; j < 16; ++j) {
        uint32_t o0, o1;
        threefry(0u, tb + (uint32_t)j, o0, o1);
        uint32_t b = o0 ^ o1;
        float f = __uint_as_float((b >> 9) | 0x3F800000u) - 1.0f;
        float u = fmaxf(1.17549435e-38f, f);
        float v = __log2f(u) * m[j];
        if (v > bv) { bv = v; bi = (uint32_t)(base + j); }
      }
#pragma unroll
      for (int off = 32; off; off >>= 1) {
        float ov = __shfl_xor(bv, off, 64);
        uint32_t oi = __shfl_xor(bi, off, 64);
        if (ov > bv || (ov == bv && oi < bi)) { bv = ov; bi = oi; }
      }
      // per-lane count registers (static indices only)
#pragma unroll
      for (int i = 0; i < 16; ++i)
        c[i] += (bi == (uint32_t)(base + i)) ? 1.f : 0.f;
      // quantized gather (bi wave-uniform; codebook is L2-hot)
      const float* cr = CW + (size_t)bi * DM + l * 8;
      float4 g0 = *(const float4*)cr;
      float4 g1 = *(const float4*)(cr + 4);
      q[0] += g0.x; q[1] += g0.y; q[2] += g0.z; q[3] += g0.w;
      q[4] += g1.x; q[5] += g1.y; q[6] += g1.z; q[7] += g1.w;
      if (l == 0) atomicAdd(&cnt[bi], 1.0f);
    }
  } else {
    if (l == 0) c[0] = 10.f;   // padded row: all 10 draws = code 0
  }

  // counts write (overwrites this row's logits)
  float* so = sout + (size_t)n * KC + base;
  *(float4*)(so)      = make_float4(c[0],  c[1],  c[2],  c[3]);
  *(float4*)(so + 4)  = make_float4(c[4],  c[5],  c[6],  c[7]);
  *(float4*)(so + 8)  = make_float4(c[8],  c[9],  c[10], c[11]);
  *(float4*)(so + 12) = make_float4(c[12], c[13], c[14], c[15]);

  // straight-through + loss (pad rows: q=0 -> st = fl(x+(0-x)) = 0, loss += x^2)
  const float* xr = X + (size_t)n * DM + l * 8;
  float4 x0 = *(const float4*)xr, x1 = *(const float4*)(xr + 4);
  float xs[8] = {x0.x, x0.y, x0.z, x0.w, x1.x, x1.y, x1.z, x1.w};
  float st[8];
  double ls = 0.0;
#pragma unroll
  for (int j = 0; j < 8; ++j) {
    float qq = q[j] / 10.0f;
    float d = qq - xs[j];
    ls += (double)(d * d);
    st[j] = xs[j] + d;
  }
  float* qo = qout + (size_t)n * DM + l * 8;
  *(float4*)qo       = make_float4(st[0], st[1], st[2], st[3]);
  *(float4*)(qo + 4) = make_float4(st[4], st[5], st[6], st[7]);

#pragma unroll
  for (int off = 32; off; off >>= 1) ls += __shfl_xor(ls, off, 64);
  if (l == 0) lsum[tid >> 6] = ls;
  __syncthreads();
  if (tid == 0) atomicAdd(esum, lsum[0] + lsum[1] + lsum[2] + lsum[3]);
}

// ---------------- scalars: loss + perplexity ----------------
__global__ __launch_bounds__(256) void k_final(const uint8_t* __restrict__ wm,
                                               const float* __restrict__ cnt,
                                               const double* __restrict__ esum,
                                               float* __restrict__ scal) {
  __shared__ int sni[256];
  __shared__ double snd[256];
  int t = threadIdx.x;
  int np = 0;
  for (int i = t; i < NROWS; i += 256) np += wm[i];
  sni[t] = np;
  __syncthreads();
  for (int off = 128; off; off >>= 1) {
    if (t < off) sni[t] += sni[t + off];
    __syncthreads();
  }
  int npad = sni[0];
  double ss = 0.0;
  for (int k = t; k < KC; k += 256) {
    float c = (k == 0) ? (float)(npad * 10) : cnt[k];
    float p = c / 327680.0f;   // / (N * NUM_SAMPLES)
    ss += (double)(p * logf(p + 1e-10f));
  }
  snd[t] = ss;
  __syncthreads();
  for (int off = 128; off; off >>= 1) {
    if (t < off) snd[t] += snd[t + off];
    __syncthreads();
  }
  if (t == 0) {
    float num_nonpad = (float)((NROWS - npad) * DM);
    float el = (float)(*esum) / num_nonpad;
    scal[0] = 0.25f * el;               // loss
    scal[1] = expf(-(float)snd[0]);     // perplexity
  }
}

extern "C" void kernel_launch(void* const* d_in, const int* in_sizes, int n_in,
                              void* d_out, int out_size, void* d_ws, size_t ws_size,
                              hipStream_t stream) {
  const float* X  = (const float*)d_in[0];
  const void*  M  = d_in[1];
  const float* CW = (const float*)d_in[2];
  float* out  = (float*)d_out;
  float* qout = out;                    // [0, 16777216): quantized_st
  float* sout = out + 16777216;         // [.., 50331648): logits scratch -> samples
  float* scal = out + 50331648;         // loss, perplexity
  uint8_t* ws = (uint8_t*)d_ws;
  double*   esum = (double*)ws;         // 8 B
  uint32_t* flag = (uint32_t*)(ws + 8); // 4 B
  float*    cnt  = (float*)(ws + 16);   // 4 KB (per-code totals)
  uint8_t*  wm   = ws + 8192;           // 32 KB (normalized byte mask)
  float*    cng  = (float*)(ws + 40960);// 4 KB (codebook row norms)
  (void)in_sizes; (void)n_in; (void)out_size; (void)ws_size;

  hipMemsetAsync(d_ws, 0, 45056, stream);
  k_detect<<<1, 256, 0, stream>>>((const uint8_t*)M, flag);
  k_mask<<<128, 256, 0, stream>>>(M, flag, wm);
  k_cnorm<<<KC, 64, 0, stream>>>(CW, cng);
  k_gemm2<<<2048, 256, 0, stream>>>(X, CW, cng, sout);   // logits into samples region
  k_sample<<<8192, 256, 0, stream>>>(sout, X, CW, wm, qout, sout, cnt, esum);
  k_final<<<1, 256, 0, stream>>>(wm, cnt, esum, scal);
}

// Round 5
// 659.062 us; speedup vs baseline: 1.6917x; 1.0175x over previous
//
#include <hip/hip_runtime.h>
#include <stdint.h>

#define NROWS 32768
#define KC 1024
#define DM 512
#define NKPROD 33554432u   // NROWS*KC

typedef _Float16 v8h __attribute__((ext_vector_type(8)));
typedef float v4f __attribute__((ext_vector_type(4)));

// ---------------- threefry2x32 (JAX-exact, key = (0, 42)) ----------------
__device__ __forceinline__ uint32_t rotl32(uint32_t x, int d) {
  return __builtin_amdgcn_alignbit(x, x, 32 - d);   // v_alignbit_b32: 1 inst
}

__device__ __forceinline__ void threefry(uint32_t x0, uint32_t x1,
                                         uint32_t& o0, uint32_t& o1) {
  const uint32_t ks0 = 0u, ks1 = 42u, ks2 = 0x1BD11BF0u;  // 0^42^0x1BD11BDA
  x0 += ks0; x1 += ks1;
#define TFR(r) { x0 += x1; x1 = rotl32(x1, r); x1 ^= x0; }
  TFR(13) TFR(15) TFR(26) TFR(6)
  x0 += ks1; x1 += ks2 + 1u;
  TFR(17) TFR(29) TFR(16) TFR(24)
  x0 += ks2; x1 += ks0 + 2u;
  TFR(13) TFR(15) TFR(26) TFR(6)
  x0 += ks0; x1 += ks1 + 3u;
  TFR(17) TFR(29) TFR(16) TFR(24)
  x0 += ks1; x1 += ks2 + 4u;
  TFR(13) TFR(15) TFR(26) TFR(6)
  x0 += ks2; x1 += ks0 + 5u;
#undef TFR
  o0 = x0; o1 = x1;
}

// ---------------- mask dtype detection + normalization ----------------
__global__ __launch_bounds__(256) void k_detect(const uint8_t* __restrict__ m,
                                                uint32_t* __restrict__ flag) {
  uint32_t f = 0;
  for (int i = threadIdx.x; i < NROWS; i += 256)
    if ((i & 3) && m[i]) f = 1;   // nonzero high byte => 1-byte bool layout
  if (f) atomicOr(flag, 1u);
}

__global__ __launch_bounds__(256) void k_mask(const void* __restrict__ m,
                                              const uint32_t* __restrict__ flag,
                                              uint8_t* __restrict__ wm) {
  int n = blockIdx.x * 256 + threadIdx.x;
  bool p = (*flag) ? (((const uint8_t*)m)[n] != 0)
                   : (((const int*)m)[n] != 0);
  wm[n] = p ? 1u : 0u;
}

// ---------------- codebook row norms ----------------
__global__ __launch_bounds__(64) void k_cnorm(const float* __restrict__ B,
                                              float* __restrict__ cn) {
  int k = blockIdx.x, l = threadIdx.x;
  const float* bp = B + (size_t)k * DM + l * 8;
  float4 v0 = *(const float4*)bp, v1 = *(const float4*)(bp + 4);
  float s = v0.x*v0.x + v0.y*v0.y + v0.z*v0.z + v0.w*v0.w
          + v1.x*v1.x + v1.y*v1.y + v1.z*v1.z + v1.w*v1.w;
#pragma unroll
  for (int off = 32; off; off >>= 1) s += __shfl_xor(s, off, 64);
  if (l == 0) cn[k] = s;
}

// ---------------- logits GEMM (MFMA, f16 two-term split) ----------------
// S[n,k] = -((||x||^2 + ||c||^2) - 2 x.c), dot via hi*hi + hi*lo + lo*hi.
#define LDK 40   // padded BK stride in f16 (80 B, 16B-aligned, conflict-light)
__global__ __launch_bounds__(256) void k_gemm2(const float* __restrict__ A,
                                               const float* __restrict__ B,
                                               const float* __restrict__ cn,
                                               float* __restrict__ S) {
  __shared__ _Float16 Ah[128 * LDK], Al[128 * LDK];
  __shared__ _Float16 Bh[128 * LDK], Bl[128 * LDK];
  __shared__ float rs[128];
  __shared__ float tmp[256];

  int tid = threadIdx.x;
  int bx = blockIdx.x & 7;           // N panel (consecutive bids share A-panel)
  int by = blockIdx.x >> 3;          // M panel
  int r0 = by * 128, c0 = bx * 128;

  int wid = tid >> 6;
  int wr = wid >> 1, wc = wid & 1;   // wave sub-tile (64x64)
  int l = tid & 63;
  int lr = l & 15;
  int k8 = (l >> 4) * 8;

  int srow = tid >> 1;               // staging row 0..127
  int ssub = (tid & 1) * 16;         // staging k sub-offset

  const float* ag = A + (size_t)(r0 + srow) * DM + ssub;
  const float* bg = B + (size_t)(c0 + srow) * DM + ssub;

  v4f acc[4][4];
#pragma unroll
  for (int m = 0; m < 4; ++m)
#pragma unroll
    for (int n = 0; n < 4; ++n) acc[m][n] = (v4f)0.0f;

  float sqa = 0.f;

  for (int k0 = 0; k0 < DM; k0 += 32) {
    // load + split
    float xa[16], xb[16];
#pragma unroll
    for (int i = 0; i < 16; i += 4) {
      *(float4*)&xa[i] = *(const float4*)(ag + k0 + i);
      *(float4*)&xb[i] = *(const float4*)(bg + k0 + i);
    }
    _Float16 ha[16], la[16], hb[16], lb[16];
#pragma unroll
    for (int i = 0; i < 16; ++i) {
      float x = xa[i];
      _Float16 h = (_Float16)x;
      ha[i] = h; la[i] = (_Float16)(x - (float)h);
      sqa = fmaf(x, x, sqa);
      float y = xb[i];
      _Float16 g = (_Float16)y;
      hb[i] = g; lb[i] = (_Float16)(y - (float)g);
    }
    __syncthreads();   // previous iter's frag reads done
    int wb = srow * LDK + ssub;
    *(v8h*)&Ah[wb]     = *(v8h*)&ha[0];
    *(v8h*)&Ah[wb + 8] = *(v8h*)&ha[8];
    *(v8h*)&Al[wb]     = *(v8h*)&la[0];
    *(v8h*)&Al[wb + 8] = *(v8h*)&la[8];
    *(v8h*)&Bh[wb]     = *(v8h*)&hb[0];
    *(v8h*)&Bh[wb + 8] = *(v8h*)&hb[8];
    *(v8h*)&Bl[wb]     = *(v8h*)&lb[0];
    *(v8h*)&Bl[wb + 8] = *(v8h*)&lb[8];
    __syncthreads();

    v8h fah[4], fal[4];
#pragma unroll
    for (int m = 0; m < 4; ++m) {
      int row = wr * 64 + m * 16 + lr;
      fah[m] = *(const v8h*)&Ah[row * LDK + k8];
      fal[m] = *(const v8h*)&Al[row * LDK + k8];
    }
#pragma unroll
    for (int n = 0; n < 4; ++n) {
      int col = wc * 64 + n * 16 + lr;
      v8h fbh = *(const v8h*)&Bh[col * LDK + k8];
      v8h fbl = *(const v8h*)&Bl[col * LDK + k8];
#pragma unroll
      for (int m = 0; m < 4; ++m) {
        acc[m][n] = __builtin_amdgcn_mfma_f32_16x16x32_f16(fah[m], fbh, acc[m][n], 0, 0, 0);
        acc[m][n] = __builtin_amdgcn_mfma_f32_16x16x32_f16(fah[m], fbl, acc[m][n], 0, 0, 0);
        acc[m][n] = __builtin_amdgcn_mfma_f32_16x16x32_f16(fal[m], fbh, acc[m][n], 0, 0, 0);
      }
    }
  }

  // row norms (fused: each thread summed its staged A elements)
  tmp[tid] = sqa;
  __syncthreads();
  if ((tid & 1) == 0) rs[srow] = tmp[tid] + tmp[tid + 1];
  __syncthreads();

  float cnp[4];
#pragma unroll
  for (int n = 0; n < 4; ++n) cnp[n] = cn[c0 + wc * 64 + n * 16 + lr];

#pragma unroll
  for (int m = 0; m < 4; ++m) {
    int rl = wr * 64 + m * 16 + (l >> 4) * 4;
#pragma unroll
    for (int r = 0; r < 4; ++r) {
      float rq = rs[rl + r];
      float* sp = S + (size_t)(r0 + rl + r) * KC + c0;
#pragma unroll
      for (int n = 0; n < 4; ++n) {
        int cl = wc * 64 + n * 16 + lr;
        sp[cl] = -((rq + cnp[n]) - 2.0f * acc[m][n][r]);
      }
    }
  }
}

// ---------------- sampling + outputs (4 INDEPENDENT waves/block) ----------------
// Partitionable-threefry bits: element t of the (10,N,K) gumbel tensor gets
// bits = o0 ^ o1 of threefry(key, (0, t)).
// argmax_k(g_k + l_k) == argmax_k fl(log2(u_k) * m_k), m_k = ln2*exp(lmax-l_k).
// No LDS, no barriers: pad-row waves retire immediately, freeing wave slots
// (R4's trailing __syncthreads stalled ~half the resident waves -> occ 46%).
__global__ __launch_bounds__(256) void k_sample(
    const float* __restrict__ S, const float* __restrict__ X,
    const float* __restrict__ CW, const uint8_t* __restrict__ wm,
    float* __restrict__ qout, float* __restrict__ sout,
    float* __restrict__ cnt, double* __restrict__ esum) {
  int tid = threadIdx.x;
  int n = blockIdx.x * 4 + (tid >> 6);
  int l = tid & 63;
  int base = l * 16;
  bool pad = wm[n] != 0;

  float c[16];
#pragma unroll
  for (int i = 0; i < 16; ++i) c[i] = 0.f;
  float q[8];
#pragma unroll
  for (int i = 0; i < 8; ++i) q[i] = 0.f;

  if (!pad) {
    const float* srow = S + (size_t)n * KC + base;
    float lg[16];
#pragma unroll
    for (int j = 0; j < 16; j += 4)
      *(float4*)&lg[j] = *(const float4*)(srow + j);
    if (l == 0) lg[0] = -__builtin_inff();  // code 0 disallowed

    float lmax = lg[0];
#pragma unroll
    for (int i = 1; i < 16; ++i) lmax = fmaxf(lmax, lg[i]);
#pragma unroll
    for (int off = 32; off; off >>= 1)
      lmax = fmaxf(lmax, __shfl_xor(lmax, off, 64));

    float m[16];
#pragma unroll
    for (int i = 0; i < 16; ++i)
      m[i] = 0.69314718056f * __expf(lmax - lg[i]);  // lane0 i=0 -> inf (never wins)

#pragma unroll 1
    for (int s = 0; s < 10; ++s) {
      uint32_t tb = (uint32_t)s * NKPROD + (uint32_t)n * (uint32_t)KC + (uint32_t)base;
      float bv = -__builtin_inff();
      uint32_t bi = 0xFFFFFFFFu;
#pragma unroll
      for (int j = 0; j < 16; ++j) {
        uint32_t o0, o1;
        threefry(0u, tb + (uint32_t)j, o0, o1);
        uint32_t b = o0 ^ o1;
        float f = __uint_as_float((b >> 9) | 0x3F800000u) - 1.0f;
        float u = fmaxf(1.17549435e-38f, f);
        float v = __log2f(u) * m[j];
        if (v > bv) { bv = v; bi = (uint32_t)(base + j); }
      }
#pragma unroll
      for (int off = 32; off; off >>= 1) {
        float ov = __shfl_xor(bv, off, 64);
        uint32_t oi = __shfl_xor(bi, off, 64);
        if (ov > bv || (ov == bv && oi < bi)) { bv = ov; bi = oi; }
      }
      // per-lane count registers (static indices only)
#pragma unroll
      for (int i = 0; i < 16; ++i)
        c[i] += (bi == (uint32_t)(base + i)) ? 1.f : 0.f;
      // quantized gather (bi wave-uniform; codebook is L2-hot)
      const float* cr = CW + (size_t)bi * DM + l * 8;
      float4 g0 = *(const float4*)cr;
      float4 g1 = *(const float4*)(cr + 4);
      q[0] += g0.x; q[1] += g0.y; q[2] += g0.z; q[3] += g0.w;
      q[4] += g1.x; q[5] += g1.y; q[6] += g1.z; q[7] += g1.w;
      if (l == 0) atomicAdd(&cnt[bi], 1.0f);
    }
  } else {
    if (l == 0) c[0] = 10.f;   // padded row: all 10 draws = code 0
  }

  // counts write (overwrites this row's logits)
  float* so = sout + (size_t)n * KC + base;
  *(float4*)(so)      = make_float4(c[0],  c[1],  c[2],  c[3]);
  *(float4*)(so + 4)  = make_float4(c[4],  c[5],  c[6],  c[7]);
  *(float4*)(so + 8)  = make_float4(c[8],  c[9],  c[10], c[11]);
  *(float4*)(so + 12) = make_float4(c[12], c[13], c[14], c[15]);

  // straight-through + loss (pad rows: q=0 -> st = fl(x+(0-x)) = 0, loss += x^2)
  const float* xr = X + (size_t)n * DM + l * 8;
  float4 x0 = *(const float4*)xr, x1 = *(const float4*)(xr + 4);
  float xs[8] = {x0.x, x0.y, x0.z, x0.w, x1.x, x1.y, x1.z, x1.w};
  float st[8];
  double ls = 0.0;
#pragma unroll
  for (int j = 0; j < 8; ++j) {
    float qq = q[j] / 10.0f;
    float d = qq - xs[j];
    ls += (double)(d * d);
    st[j] = xs[j] + d;
  }
  float* qo = qout + (size_t)n * DM + l * 8;
  *(float4*)qo       = make_float4(st[0], st[1], st[2], st[3]);
  *(float4*)(qo + 4) = make_float4(st[4], st[5], st[6], st[7]);

#pragma unroll
  for (int off = 32; off; off >>= 1) ls += __shfl_xor(ls, off, 64);
  if (l == 0) atomicAdd(&esum[n & 63], ls);   // 64 striped slots, low contention
}

// ---------------- scalars: loss + perplexity ----------------
__global__ __launch_bounds__(256) void k_final(const uint8_t* __restrict__ wm,
                                               const float* __restrict__ cnt,
                                               const double* __restrict__ esum,
                                               float* __restrict__ scal) {
  __shared__ int sni[256];
  __shared__ double snd[256];
  int t = threadIdx.x;
  int np = 0;
  for (int i = t; i < NROWS; i += 256) np += wm[i];
  sni[t] = np;
  __syncthreads();
  for (int off = 128; off; off >>= 1) {
    if (t < off) sni[t] += sni[t + off];
    __syncthreads();
  }
  int npad = sni[0];
  double ss = 0.0;
  for (int k = t; k < KC; k += 256) {
    float c = (k == 0) ? (float)(npad * 10) : cnt[k];
    float p = c / 327680.0f;   // / (N * NUM_SAMPLES)
    ss += (double)(p * logf(p + 1e-10f));
  }
  snd[t] = ss;
  __syncthreads();
  for (int off = 128; off; off >>= 1) {
    if (t < off) snd[t] += snd[t + off];
    __syncthreads();
  }
  if (t == 0) {
    double es = 0.0;
    for (int i = 0; i < 64; ++i) es += esum[i];
    float num_nonpad = (float)((NROWS - npad) * DM);
    float el = (float)es / num_nonpad;
    scal[0] = 0.25f * el;               // loss
    scal[1] = expf(-(float)snd[0]);     // perplexity
  }
}

extern "C" void kernel_launch(void* const* d_in, const int* in_sizes, int n_in,
                              void* d_out, int out_size, void* d_ws, size_t ws_size,
                              hipStream_t stream) {
  const float* X  = (const float*)d_in[0];
  const void*  M  = d_in[1];
  const float* CW = (const float*)d_in[2];
  float* out  = (float*)d_out;
  float* qout = out;                    // [0, 16777216): quantized_st
  float* sout = out + 16777216;         // [.., 50331648): logits scratch -> samples
  float* scal = out + 50331648;         // loss, perplexity
  uint8_t* ws = (uint8_t*)d_ws;
  double*   esum = (double*)ws;         // 512 B (64 striped slots)
  uint32_t* flag = (uint32_t*)(ws + 512);
  float*    cnt  = (float*)(ws + 1024); // 4 KB (per-code totals)
  uint8_t*  wm   = ws + 8192;           // 32 KB (normalized byte mask)
  float*    cng  = (float*)(ws + 40960);// 4 KB (codebook row norms)
  (void)in_sizes; (void)n_in; (void)out_size; (void)ws_size;

  hipMemsetAsync(d_ws, 0, 45056, stream);
  k_detect<<<1, 256, 0, stream>>>((const uint8_t*)M, flag);
  k_mask<<<128, 256, 0, stream>>>(M, flag, wm);
  k_cnorm<<<KC, 64, 0, stream>>>(CW, cng);
  k_gemm2<<<2048, 256, 0, stream>>>(X, CW, cng, sout);   // logits into samples region
  k_sample<<<8192, 256, 0, stream>>>(sout, X, CW, wm, qout, sout, cnt, esum);
  k_final<<<1, 256, 0, stream>>>(wm, cnt, esum, scal);
}

// Round 6
// 566.996 us; speedup vs baseline: 1.9664x; 1.1624x over previous
//
#include <hip/hip_runtime.h>
#include <stdint.h>

#define NROWS 32768
#define KC 1024
#define DM 512
#define NKPROD 33554432u   // NROWS*KC

typedef _Float16 v8h __attribute__((ext_vector_type(8)));
typedef float v4f __attribute__((ext_vector_type(4)));

// ---------------- threefry2x32 (JAX-exact, key = (0, 42)) ----------------
__device__ __forceinline__ uint32_t rotl32(uint32_t x, int d) {
  return __builtin_amdgcn_alignbit(x, x, 32 - d);   // v_alignbit_b32: 1 inst
}

__device__ __forceinline__ void threefry(uint32_t x0, uint32_t x1,
                                         uint32_t& o0, uint32_t& o1) {
  const uint32_t ks0 = 0u, ks1 = 42u, ks2 = 0x1BD11BF0u;  // 0^42^0x1BD11BDA
  x0 += ks0; x1 += ks1;
#define TFR(r) { x0 += x1; x1 = rotl32(x1, r); x1 ^= x0; }
  TFR(13) TFR(15) TFR(26) TFR(6)
  x0 += ks1; x1 += ks2 + 1u;
  TFR(17) TFR(29) TFR(16) TFR(24)
  x0 += ks2; x1 += ks0 + 2u;
  TFR(13) TFR(15) TFR(26) TFR(6)
  x0 += ks0; x1 += ks1 + 3u;
  TFR(17) TFR(29) TFR(16) TFR(24)
  x0 += ks1; x1 += ks2 + 4u;
  TFR(13) TFR(15) TFR(26) TFR(6)
  x0 += ks2; x1 += ks0 + 5u;
#undef TFR
  o0 = x0; o1 = x1;
}

// ---------------- prep: mask detect + normalize + compact non-pad rows ----------------
// Single block, 1024 threads, 32 rows/thread. Order-preserving compaction.
__global__ __launch_bounds__(1024) void k_prep(const void* __restrict__ mv,
                                               uint8_t* __restrict__ wm,
                                               int* __restrict__ idx,
                                               int* __restrict__ npp) {
  __shared__ uint32_t sflag;
  __shared__ int scnt[1024];
  int t = threadIdx.x;
  if (t == 0) sflag = 0;
  __syncthreads();
  const uint8_t* mb = (const uint8_t*)mv;
  uint32_t f = 0;
  for (int i = t; i < NROWS; i += 1024)
    if ((i & 3) && mb[i]) f = 1;   // nonzero high byte => 1-byte bool layout
  if (f) atomicOr(&sflag, 1u);
  __syncthreads();
  bool isbool = sflag != 0;

  int r0 = t * 32;
  int cnt = 0;
  for (int i = 0; i < 32; ++i) {
    int r = r0 + i;
    bool p = isbool ? (mb[r] != 0) : (((const int*)mv)[r] != 0);
    wm[r] = p ? 1u : 0u;
    cnt += p ? 0 : 1;
  }
  scnt[t] = cnt;
  __syncthreads();
  // Hillis-Steele inclusive scan over 1024
  for (int off = 1; off < 1024; off <<= 1) {
    int v = (t >= off) ? scnt[t - off] : 0;
    __syncthreads();
    scnt[t] += v;
    __syncthreads();
  }
  int pos = scnt[t] - cnt;   // exclusive prefix
  for (int i = 0; i < 32; ++i) {
    int r = r0 + i;
    bool p = isbool ? (mb[r] != 0) : (((const int*)mv)[r] != 0);
    if (!p) idx[pos++] = r;
  }
  if (t == 1023) *npp = scnt[1023];
}

// ---------------- pad rows: counts(c0=10), qout zeros, loss += x^2 ----------------
__global__ __launch_bounds__(256) void k_pad(const float* __restrict__ X,
                                             const uint8_t* __restrict__ wm,
                                             float* __restrict__ qout,
                                             float* __restrict__ sout,
                                             double* __restrict__ esum) {
  int n = blockIdx.x * 4 + (threadIdx.x >> 6);
  int l = threadIdx.x & 63;
  if (!wm[n]) return;   // non-pad handled by k_sample_i (wave-uniform exit)

  float* so = sout + (size_t)n * KC + l * 16;
  float4 z = make_float4(0.f, 0.f, 0.f, 0.f);
  *(float4*)(so)      = (l == 0) ? make_float4(10.f, 0.f, 0.f, 0.f) : z;
  *(float4*)(so + 4)  = z;
  *(float4*)(so + 8)  = z;
  *(float4*)(so + 12) = z;

  const float* xr = X + (size_t)n * DM + l * 8;
  float4 x0 = *(const float4*)xr, x1 = *(const float4*)(xr + 4);
  float* qo = qout + (size_t)n * DM + l * 8;
  *(float4*)qo       = z;
  *(float4*)(qo + 4) = z;
  double ls = (double)(x0.x*x0.x) + (double)(x0.y*x0.y)
            + (double)(x0.z*x0.z) + (double)(x0.w*x0.w)
            + (double)(x1.x*x1.x) + (double)(x1.y*x1.y)
            + (double)(x1.z*x1.z) + (double)(x1.w*x1.w);
#pragma unroll
  for (int off = 32; off; off >>= 1) ls += __shfl_xor(ls, off, 64);
  if (l == 0) atomicAdd(&esum[n & 63], ls);
}

// ---------------- codebook row norms ----------------
__global__ __launch_bounds__(64) void k_cnorm(const float* __restrict__ B,
                                              float* __restrict__ cn) {
  int k = blockIdx.x, l = threadIdx.x;
  const float* bp = B + (size_t)k * DM + l * 8;
  float4 v0 = *(const float4*)bp, v1 = *(const float4*)(bp + 4);
  float s = v0.x*v0.x + v0.y*v0.y + v0.z*v0.z + v0.w*v0.w
          + v1.x*v1.x + v1.y*v1.y + v1.z*v1.z + v1.w*v1.w;
#pragma unroll
  for (int off = 32; off; off >>= 1) s += __shfl_xor(s, off, 64);
  if (l == 0) cn[k] = s;
}

// ---------------- logits GEMM on compacted rows (MFMA, f16 two-term split) ----------------
// S[idx[slot],k] = -((||x||^2 + ||c||^2) - 2 x.c); tail slots clamp to idx[NP-1]
// (duplicate identical writes, benign).
#define LDK 40   // padded BK stride in f16 (80 B, 16B-aligned, conflict-light)
__global__ __launch_bounds__(256) void k_gemm2i(const float* __restrict__ A,
                                                const float* __restrict__ B,
                                                const float* __restrict__ cn,
                                                const int* __restrict__ idx,
                                                const int* __restrict__ npp,
                                                float* __restrict__ S) {
  int NP = *npp;
  int bx = blockIdx.x & 7;           // N panel
  int by = blockIdx.x >> 3;          // M panel (compact slots)
  int r0 = by * 128, c0 = bx * 128;
  if (r0 >= NP) return;

  __shared__ _Float16 Ah[128 * LDK], Al[128 * LDK];
  __shared__ _Float16 Bh[128 * LDK], Bl[128 * LDK];
  __shared__ float rs[128];
  __shared__ float tmp[256];

  int tid = threadIdx.x;
  int wid = tid >> 6;
  int wr = wid >> 1, wc = wid & 1;   // wave sub-tile (64x64)
  int l = tid & 63;
  int lr = l & 15;
  int k8 = (l >> 4) * 8;

  int srow = tid >> 1;               // staging slot-row 0..127
  int ssub = (tid & 1) * 16;         // staging k sub-offset

  int slot = r0 + srow;
  int orig = idx[slot < NP ? slot : NP - 1];
  const float* ag = A + (size_t)orig * DM + ssub;
  const float* bg = B + (size_t)(c0 + srow) * DM + ssub;

  v4f acc[4][4];
#pragma unroll
  for (int m = 0; m < 4; ++m)
#pragma unroll
    for (int n = 0; n < 4; ++n) acc[m][n] = (v4f)0.0f;

  float sqa = 0.f;

  for (int k0 = 0; k0 < DM; k0 += 32) {
    float xa[16], xb[16];
#pragma unroll
    for (int i = 0; i < 16; i += 4) {
      *(float4*)&xa[i] = *(const float4*)(ag + k0 + i);
      *(float4*)&xb[i] = *(const float4*)(bg + k0 + i);
    }
    _Float16 ha[16], la[16], hb[16], lb[16];
#pragma unroll
    for (int i = 0; i < 16; ++i) {
      float x = xa[i];
      _Float16 h = (_Float16)x;
      ha[i] = h; la[i] = (_Float16)(x - (float)h);
      sqa = fmaf(x, x, sqa);
      float y = xb[i];
      _Float16 g = (_Float16)y;
      hb[i] = g; lb[i] = (_Float16)(y - (float)g);
    }
    __syncthreads();   // previous iter's frag reads done
    int wb = srow * LDK + ssub;
    *(v8h*)&Ah[wb]     = *(v8h*)&ha[0];
    *(v8h*)&Ah[wb + 8] = *(v8h*)&ha[8];
    *(v8h*)&Al[wb]     = *(v8h*)&la[0];
    *(v8h*)&Al[wb + 8] = *(v8h*)&la[8];
    *(v8h*)&Bh[wb]     = *(v8h*)&hb[0];
    *(v8h*)&Bh[wb + 8] = *(v8h*)&hb[8];
    *(v8h*)&Bl[wb]     = *(v8h*)&lb[0];
    *(v8h*)&Bl[wb + 8] = *(v8h*)&lb[8];
    __syncthreads();

    v8h fah[4], fal[4];
#pragma unroll
    for (int m = 0; m < 4; ++m) {
      int row = wr * 64 + m * 16 + lr;
      fah[m] = *(const v8h*)&Ah[row * LDK + k8];
      fal[m] = *(const v8h*)&Al[row * LDK + k8];
    }
#pragma unroll
    for (int n = 0; n < 4; ++n) {
      int col = wc * 64 + n * 16 + lr;
      v8h fbh = *(const v8h*)&Bh[col * LDK + k8];
      v8h fbl = *(const v8h*)&Bl[col * LDK + k8];
#pragma unroll
      for (int m = 0; m < 4; ++m) {
        acc[m][n] = __builtin_amdgcn_mfma_f32_16x16x32_f16(fah[m], fbh, acc[m][n], 0, 0, 0);
        acc[m][n] = __builtin_amdgcn_mfma_f32_16x16x32_f16(fah[m], fbl, acc[m][n], 0, 0, 0);
        acc[m][n] = __builtin_amdgcn_mfma_f32_16x16x32_f16(fal[m], fbh, acc[m][n], 0, 0, 0);
      }
    }
  }

  // row norms (fused: each thread summed its gathered A elements)
  tmp[tid] = sqa;
  __syncthreads();
  if ((tid & 1) == 0) rs[srow] = tmp[tid] + tmp[tid + 1];
  __syncthreads();

  float cnp[4];
#pragma unroll
  for (int n = 0; n < 4; ++n) cnp[n] = cn[c0 + wc * 64 + n * 16 + lr];

#pragma unroll
  for (int m = 0; m < 4; ++m) {
    int rl = wr * 64 + m * 16 + (l >> 4) * 4;
#pragma unroll
    for (int r = 0; r < 4; ++r) {
      int sl = r0 + rl + r;
      int org = idx[sl < NP ? sl : NP - 1];
      float rq = rs[rl + r];
      float* sp = S + (size_t)org * KC + c0;
#pragma unroll
      for (int n = 0; n < 4; ++n) {
        int cl = wc * 64 + n * 16 + lr;
        sp[cl] = -((rq + cnp[n]) - 2.0f * acc[m][n][r]);
      }
    }
  }
}

// ---------------- sampling on compacted non-pad rows (uniform waves) ----------------
// Bit-identical draw stream to R5: bits = o0^o1 of threefry(key,(0,t));
// argmax_k(g_k+l_k) == argmax_k fl(log2(u_k)*m_k), m_k = ln2*exp(lmax-l_k).
// __launch_bounds__(256,4): 128-VGPR cap keeps m[16]/c[16]/q[8] in registers
// (R5's 44-VGPR allocation spilled them to scratch).
__global__ __launch_bounds__(256, 4) void k_sample_i(
    const float* __restrict__ S, const float* __restrict__ X,
    const float* __restrict__ CW, const int* __restrict__ idx,
    const int* __restrict__ npp,
    float* __restrict__ qout, float* __restrict__ sout,
    float* __restrict__ cnt, double* __restrict__ esum) {
  int NP = *npp;
  int slot = blockIdx.x * 4 + (threadIdx.x >> 6);
  if (slot >= NP) return;   // wave-uniform exit
  int n = idx[slot];
  int l = threadIdx.x & 63;
  int base = l * 16;

  float c[16];
#pragma unroll
  for (int i = 0; i < 16; ++i) c[i] = 0.f;
  float q[8];
#pragma unroll
  for (int i = 0; i < 8; ++i) q[i] = 0.f;

  const float* srow = S + (size_t)n * KC + base;
  float lg[16];
#pragma unroll
  for (int j = 0; j < 16; j += 4)
    *(float4*)&lg[j] = *(const float4*)(srow + j);
  if (l == 0) lg[0] = -__builtin_inff();  // code 0 disallowed

  float lmax = lg[0];
#pragma unroll
  for (int i = 1; i < 16; ++i) lmax = fmaxf(lmax, lg[i]);
#pragma unroll
  for (int off = 32; off; off >>= 1)
    lmax = fmaxf(lmax, __shfl_xor(lmax, off, 64));

  float m[16];
#pragma unroll
  for (int i = 0; i < 16; ++i)
    m[i] = 0.69314718056f * __expf(lmax - lg[i]);  // lane0 i=0 -> inf (never wins)

#pragma unroll 1
  for (int s = 0; s < 10; ++s) {
    uint32_t tb = (uint32_t)s * NKPROD + (uint32_t)n * (uint32_t)KC + (uint32_t)base;
    float bv = -__builtin_inff();
    uint32_t bi = 0xFFFFFFFFu;
#pragma unroll
    for (int j = 0; j < 16; ++j) {
      uint32_t o0, o1;
      threefry(0u, tb + (uint32_t)j, o0, o1);
      uint32_t b = o0 ^ o1;
      float f = __uint_as_float((b >> 9) | 0x3F800000u) - 1.0f;
      float u = fmaxf(1.17549435e-38f, f);
      float v = __log2f(u) * m[j];
      if (v > bv) { bv = v; bi = (uint32_t)(base + j); }
    }
#pragma unroll
    for (int off = 32; off; off >>= 1) {
      float ov = __shfl_xor(bv, off, 64);
      uint32_t oi = __shfl_xor(bi, off, 64);
      if (ov > bv || (ov == bv && oi < bi)) { bv = ov; bi = oi; }
    }
#pragma unroll
    for (int i = 0; i < 16; ++i)
      c[i] += (bi == (uint32_t)(base + i)) ? 1.f : 0.f;
    const float* cr = CW + (size_t)bi * DM + l * 8;
    float4 g0 = *(const float4*)cr;
    float4 g1 = *(const float4*)(cr + 4);
    q[0] += g0.x; q[1] += g0.y; q[2] += g0.z; q[3] += g0.w;
    q[4] += g1.x; q[5] += g1.y; q[6] += g1.z; q[7] += g1.w;
    if (l == 0) atomicAdd(&cnt[bi], 1.0f);
  }

  // counts write (overwrites this row's logits)
  float* so = sout + (size_t)n * KC + base;
  *(float4*)(so)      = make_float4(c[0],  c[1],  c[2],  c[3]);
  *(float4*)(so + 4)  = make_float4(c[4],  c[5],  c[6],  c[7]);
  *(float4*)(so + 8)  = make_float4(c[8],  c[9],  c[10], c[11]);
  *(float4*)(so + 12) = make_float4(c[12], c[13], c[14], c[15]);

  // straight-through + loss
  const float* xr = X + (size_t)n * DM + l * 8;
  float4 x0 = *(const float4*)xr, x1 = *(const float4*)(xr + 4);
  float xs[8] = {x0.x, x0.y, x0.z, x0.w, x1.x, x1.y, x1.z, x1.w};
  float st[8];
  double ls = 0.0;
#pragma unroll
  for (int j = 0; j < 8; ++j) {
    float qq = q[j] / 10.0f;
    float d = qq - xs[j];
    ls += (double)(d * d);
    st[j] = xs[j] + d;
  }
  float* qo = qout + (size_t)n * DM + l * 8;
  *(float4*)qo       = make_float4(st[0], st[1], st[2], st[3]);
  *(float4*)(qo + 4) = make_float4(st[4], st[5], st[6], st[7]);

#pragma unroll
  for (int off = 32; off; off >>= 1) ls += __shfl_xor(ls, off, 64);
  if (l == 0) atomicAdd(&esum[n & 63], ls);   // 64 striped slots
}

// ---------------- scalars: loss + perplexity ----------------
__global__ __launch_bounds__(256) void k_final(const uint8_t* __restrict__ wm,
                                               const float* __restrict__ cnt,
                                               const double* __restrict__ esum,
                                               float* __restrict__ scal) {
  __shared__ int sni[256];
  __shared__ double snd[256];
  int t = threadIdx.x;
  int np = 0;
  for (int i = t; i < NROWS; i += 256) np += wm[i];
  sni[t] = np;
  __syncthreads();
  for (int off = 128; off; off >>= 1) {
    if (t < off) sni[t] += sni[t + off];
    __syncthreads();
  }
  int npad = sni[0];
  double ss = 0.0;
  for (int k = t; k < KC; k += 256) {
    float c = (k == 0) ? (float)(npad * 10) : cnt[k];
    float p = c / 327680.0f;   // / (N * NUM_SAMPLES)
    ss += (double)(p * logf(p + 1e-10f));
  }
  snd[t] = ss;
  __syncthreads();
  for (int off = 128; off; off >>= 1) {
    if (t < off) snd[t] += snd[t + off];
    __syncthreads();
  }
  if (t == 0) {
    double es = 0.0;
    for (int i = 0; i < 64; ++i) es += esum[i];
    float num_nonpad = (float)((NROWS - npad) * DM);
    float el = (float)es / num_nonpad;
    scal[0] = 0.25f * el;               // loss
    scal[1] = expf(-(float)snd[0]);     // perplexity
  }
}

extern "C" void kernel_launch(void* const* d_in, const int* in_sizes, int n_in,
                              void* d_out, int out_size, void* d_ws, size_t ws_size,
                              hipStream_t stream) {
  const float* X  = (const float*)d_in[0];
  const void*  M  = d_in[1];
  const float* CW = (const float*)d_in[2];
  float* out  = (float*)d_out;
  float* qout = out;                    // [0, 16777216): quantized_st
  float* sout = out + 16777216;         // [.., 50331648): logits scratch -> samples
  float* scal = out + 50331648;         // loss, perplexity
  uint8_t* ws = (uint8_t*)d_ws;
  double*   esum = (double*)ws;         // 512 B (64 striped slots)
  float*    cnt  = (float*)(ws + 1024); // 4 KB (per-code totals)
  uint8_t*  wm   = ws + 8192;           // 32 KB (normalized byte mask)
  float*    cng  = (float*)(ws + 40960);// 4 KB (codebook row norms)
  int*      npp  = (int*)(ws + 45056);  // 4 B  (non-pad count)
  int*      idx  = (int*)(ws + 49152);  // 128 KB (compact non-pad row indices)
  (void)in_sizes; (void)n_in; (void)out_size; (void)ws_size;

  hipMemsetAsync(d_ws, 0, 8192, stream);                 // esum + cnt
  k_prep<<<1, 1024, 0, stream>>>(M, wm, idx, npp);
  k_pad<<<8192, 256, 0, stream>>>(X, wm, qout, sout, esum);
  k_cnorm<<<KC, 64, 0, stream>>>(CW, cng);
  k_gemm2i<<<2048, 256, 0, stream>>>(X, CW, cng, idx, npp, sout);
  k_sample_i<<<8192, 256, 0, stream>>>(sout, X, CW, idx, npp, qout, sout, cnt, esum);
  k_final<<<1, 256, 0, stream>>>(wm, cnt, esum, scal);
}